// Round 14
// baseline (4230.643 us; speedup 1.0000x reference)
//
#include <hip/hip_runtime.h>

#define BB  64
#define TT  256
#define INF 512
#define HH  1024
#define CC  128

typedef __attribute__((ext_vector_type(8))) short bf16x8;
typedef __attribute__((ext_vector_type(4))) float f32x4;
typedef unsigned long long ull_t;
typedef unsigned short u16;

#define W0_LD 1544   // 1536+8
#define W1_LD 2056   // 2048+8
#define WC_LD 1032   // 1024+8
#define GSC_OFF (16*W0_LD + 16*W1_LD + 16*WC_LD)
#define SMEM_BYTES (GSC_OFF*2 + 2*(4*16*17)*4 + 64)

#define HBUF (BB*HH)                 // elements per h generation (128 KB)
#define BAR_BYTES 65536

#define AGENT __HIP_MEMORY_SCOPE_AGENT
#define RLX   __ATOMIC_RELAXED

__device__ __forceinline__ u16 f2bf(float f) {
    union { float f; unsigned u; } v; v.f = f;
    unsigned r = v.u + 0x7fffu + ((v.u >> 16) & 1u);   // RNE
    return (u16)(r >> 16);
}
__device__ __forceinline__ float sigm(float x) { return 1.f / (1.f + __expf(-x)); }

#define MFMA(a,b,c) __builtin_amdgcn_mfma_f32_16x16x32_bf16((a),(b),(c),0,0,0)
#define PRIO(n) __builtin_amdgcn_s_setprio(n)

// blocked h layout: [slot][block][row 0..63][col 0..3] — block region = 512 B,
// writer wave stores 16x8B = one full 128B line; readers: 2x8B per fragment.
template<bool PLAIN>
__device__ __forceinline__ bf16x8 ld_pair(const u16* slotbase, int bb, int ar) {
    union { ull_t u[2]; bf16x8 v; } x;
    const u16* p0 = slotbase + (bb << 8) + (ar << 2);
    if constexpr (PLAIN) {
        x.u[0] = *(const ull_t*)p0;           // written once before flag -> never stale
        x.u[1] = *(const ull_t*)(p0 + 256);
    } else {
        x.u[0] = __hip_atomic_load((const ull_t*)p0,         RLX, AGENT);
        x.u[1] = __hip_atomic_load((const ull_t*)(p0 + 256), RLX, AGENT);
    }
    return x.v;
}

// direct poll over per-block flags: one pass = 16-32B/lane from this block's replica.
// BK = FMA backoff length (pickup granularity vs fabric poll rate).
#define POLL3(nF0, nF1, nFC, BK) do { \
        const unsigned _n0 = (unsigned)(nF0), _n1 = (unsigned)(nF1), _nc = (unsigned)(nFC); \
        float _z = 1.f; \
        for (;;) { \
            bool _ok = true; \
            if (_n0) { \
                ull_t _a = __hip_atomic_load(f0p + (lane << 1),     RLX, AGENT); \
                ull_t _b = __hip_atomic_load(f0p + (lane << 1) + 1, RLX, AGENT); \
                _ok &= ((unsigned)_a >= _n0) && ((unsigned)(_a >> 32) >= _n0) \
                    && ((unsigned)_b >= _n0) && ((unsigned)(_b >> 32) >= _n0); \
            } \
            if (_n1) { \
                ull_t _a = __hip_atomic_load(f1p + (lane << 1),     RLX, AGENT); \
                ull_t _b = __hip_atomic_load(f1p + (lane << 1) + 1, RLX, AGENT); \
                _ok &= ((unsigned)_a >= _n1) && ((unsigned)(_a >> 32) >= _n1) \
                    && ((unsigned)_b >= _n1) && ((unsigned)(_b >> 32) >= _n1); \
            } \
            if (_nc && lane < 16) { \
                ull_t _a = __hip_atomic_load(fcp + lane, RLX, AGENT); \
                _ok &= ((unsigned)_a >= _nc) && ((unsigned)(_a >> 32) >= _nc); \
            } \
            if (__all(_ok)) break; \
            _Pragma("unroll 16") \
            for (int _i = 0; _i < (BK); ++_i) _z = __builtin_fmaf(_z, 0.99999988f, 1e-9f); \
            asm volatile("" :: "v"(_z)); \
        } \
        asm volatile("" ::: "memory"); \
    } while (0)

template<int DEPTH, bool PLAIN>
__global__ __launch_bounds__(640, 1)
void lstm_persist(const float* __restrict__ xs,
                  const float* __restrict__ Wih0, const float* __restrict__ Whh0,
                  const float* __restrict__ bih0, const float* __restrict__ bhh0,
                  const float* __restrict__ Wih1, const float* __restrict__ Whh1,
                  const float* __restrict__ bih1, const float* __restrict__ bhh1,
                  const float* __restrict__ Wcls, const float* __restrict__ bcls,
                  float* __restrict__ out,          // f32 [B][C][2T]
                  u16* __restrict__ hws,            // h slot arrays (blocked layout)
                  unsigned* __restrict__ bar)       // f0[8][256] f1[8][256] fc[8][64]
{
    extern __shared__ char smem[];
    u16* W0s = (u16*)smem;              // [16][W0_LD]  [W_hh0 | W_ih0]
    u16* W1s = W0s + 16*W0_LD;          // [16][W1_LD]  [W_ih1 | W_hh1]
    u16* WCs = W1s + 16*W1_LD;          // [16][WC_LD]  W_cls slice
    float* gsc0 = (float*)(smem + GSC_OFF*2);       // [4][16][17]
    float* gsc1 = gsc0 + 4*16*17;
    unsigned* scnt = (unsigned*)(gsc1 + 4*16*17);   // [0]=L0 arrivals, [1]=L1 arrivals

    const int blk   = blockIdx.x;       // owns h-cols 4*blk..4*blk+3 (both layers)
    const int tid   = threadIdx.x;
    const int wave  = tid >> 6;         // 0-3: L0, 4-7: L1, 8: cls, 9: heater
    const int lane  = tid & 63;
    const int col16 = lane & 15;
    const int kgrp  = (lane >> 4) << 3;

    u16* ring0 = hws;                           // h0 value x at slot (x+2)%DEPTH
    u16* ring1 = hws + (size_t)DEPTH*HBUF;
    const ull_t* f0p = (const ull_t*)(bar + (blk & 7)*256);
    const ull_t* f1p = (const ull_t*)(bar + 2048 + (blk & 7)*256);
    const ull_t* fcp = (const ull_t*)(bar + 4096 + (blk & 7)*64);

#define SLOT(x) ((unsigned)(((x) + 2) % DEPTH))

    // ---- prologue: weights -> LDS (bf16)
    if (tid < 2) scnt[tid] = 0;
    for (int i = tid; i < 16*1536; i += 640) {
        int r = i / 1536, k = i - r*1536;
        int gr = 4*blk + (r & 3) + HH*(r >> 2);
        float v = (k < HH) ? Whh0[gr*HH + k] : Wih0[gr*INF + (k - HH)];
        W0s[r*W0_LD + k] = f2bf(v);
    }
    for (int i = tid; i < 16*2048; i += 640) {
        int r = i >> 11, k = i & 2047;
        int gr = 4*blk + (r & 3) + HH*(r >> 2);
        float v = (k < HH) ? Wih1[gr*HH + k] : Whh1[gr*HH + (k - HH)];
        W1s[r*W1_LD + k] = f2bf(v);
    }
    if (PLAIN || blk < 32) {
        int cb = (blk & 7) << 4;
        for (int i = tid; i < 16*1024; i += 640) {
            int r = i >> 10, k = i & 1023;
            WCs[r*WC_LD + k] = f2bf(Wcls[(cb + r)*HH + k]);
        }
    }
    __syncthreads();

    // ================= heater wave: keep SIMD issue-busy at prio 0 =================
    if (wave == 9) {
        PRIO(0);
        const unsigned* myf1 = bar + 2048 + (blk & 7)*256 + blk;
        float a = 1.0000001f, b = 0.99999988f;
        for (;;) {
            #pragma unroll 32
            for (int i = 0; i < 4096; ++i) a = __builtin_fmaf(a, b, 1e-9f);
            asm volatile("" :: "v"(a));
            if (__hip_atomic_load(myf1, RLX, AGENT) >= (unsigned)TT) break;
        }
        return;
    }

    // ================= classifier wave (prio 0: uses idle slots only) =================
    if (wave == 8) {
        PRIO(0);
        const u16*  wcp   = WCs + col16*WC_LD + kgrp;
        const float biasc = bcls[((blk & 7) << 4) + col16];
        const int cc = ((blk & 7) << 4) + col16;
        const int cstart = PLAIN ? (blk >> 5) : 0;
        const int cstep  = PLAIN ? 8 : 1;
        const int R      = PLAIN ? ((blk & 31) >> 3) : (blk >> 3);
        const int arow2  = (R << 4) + col16;
        if (PLAIN || blk < 32) {
            for (int c = cstart; c < TT/8; c += cstep) {
                POLL3(0, 8*c + 8, 0, 256);       // h0/h1(8c..8c+7) final everywhere
                union { float2 f2[8]; f32x4 f4[4]; } o[4];
                #pragma unroll
                for (int tt = 0; tt < 8; ++tt) {
                    const int t = 8*c + tt;
                    const u16* s0 = ring0 + (size_t)SLOT(t)*HBUF;
                    const u16* s1 = ring1 + (size_t)SLOT(t)*HBUF;
                    f32x4 a0 = { biasc, biasc, biasc, biasc }, a1 = { 0.f, 0.f, 0.f, 0.f };
                    f32x4 b0 = { biasc, biasc, biasc, biasc }, b1 = { 0.f, 0.f, 0.f, 0.f };
                    #pragma unroll 4
                    for (int kc = 0; kc < 32; ++kc) {
                        const int bb = (kgrp >> 2) + (kc << 3);
                        const bf16x8 w  = *(const bf16x8*)(wcp + (kc << 5));
                        const bf16x8 x0 = ld_pair<PLAIN>(s0, bb, arow2);
                        const bf16x8 x1 = ld_pair<PLAIN>(s1, bb, arow2);
                        if (kc & 1) { a1 = MFMA(x0, w, a1); b1 = MFMA(x1, w, b1); }
                        else        { a0 = MFMA(x0, w, a0); b0 = MFMA(x1, w, b0); }
                    }
                    #pragma unroll
                    for (int q = 0; q < 4; ++q)
                        o[q].f2[tt] = make_float2(a0[q] + a1[q], b0[q] + b1[q]);
                }
                #pragma unroll
                for (int q = 0; q < 4; ++q) {
                    const int br = (R << 4) + ((lane >> 4) << 2) + q;
                    float* po = &out[(ull_t)(br*CC + cc)*(2*TT) + 16*c];
                    #pragma unroll
                    for (int s = 0; s < 4; ++s)
                        __builtin_nontemporal_store(o[q].f4[s], (f32x4*)(po + 4*s));
                }
                if (!PLAIN) {
                    asm volatile("s_waitcnt vmcnt(0)" ::: "memory");
                    if (lane < 8)
                        __hip_atomic_store(&bar[4096 + lane*64 + blk], (unsigned)(c + 1), RLX, AGENT);
                }
            }
        }
        return;
    }

    // ================= worker waves =================
    const int wv   = wave & 3;
    const int arow = (wv << 4) + col16;
    const int rloc = lane >> 2, jj = lane & 3;
    const u16* w0p = W0s + col16*W0_LD + kgrp;
    const u16* w1p = W1s + col16*W1_LD + kgrp;
    const int  grl = 4*blk + (col16 & 3) + HH*(col16 >> 2);

    if (wave < 4) {
        // ---------- L0 worker: THE critical chain (prio 2 compute / 1 poll) ----------
        const float bias0 = bih0[grl] + bhh0[grl];
        float c0 = 0.f;
        f32x4 g0A = { bias0, bias0, bias0, bias0 }, g0B = { 0.f, 0.f, 0.f, 0.f };
        {   // prime x-projection for t=0
            const float* xp = xs + (arow*TT + 0)*INF + kgrp;
            #pragma unroll 4
            for (int kc = 0; kc < 16; ++kc) {
                const float4 x0 = *(const float4*)(xp + (kc << 5));
                const float4 x1 = *(const float4*)(xp + (kc << 5) + 4);
                bf16x8 a;
                a[0]=(short)f2bf(x0.x); a[1]=(short)f2bf(x0.y); a[2]=(short)f2bf(x0.z); a[3]=(short)f2bf(x0.w);
                a[4]=(short)f2bf(x1.x); a[5]=(short)f2bf(x1.y); a[6]=(short)f2bf(x1.z); a[7]=(short)f2bf(x1.w);
                const bf16x8 b = *(const bf16x8*)(w0p + ((32 + kc) << 5));
                if (kc & 1) g0B = MFMA(a, b, g0B); else g0A = MFMA(a, b, g0A);
            }
        }
        for (int t = 0; t < TT; ++t) {
            unsigned n1c = 0, ncc = 0;
            if constexpr (DEPTH <= TT) {            // slot-reuse credits
                if (t >= DEPTH) { n1c = (unsigned)(t - DEPTH + 1);
                                  ncc = (unsigned)((t - DEPTH)/8 + 1); }
            }
            PRIO(1);
            POLL3(t, n1c, ncc, 128);                // h0(t-1) visible everywhere
            PRIO(2);
            const u16* s0 = ring0 + (size_t)SLOT(t - 1)*HBUF;
            #pragma unroll 4
            for (int kc = 0; kc < 32; ++kc) {
                const int bb = (kgrp >> 2) + (kc << 3);
                const bf16x8 a = ld_pair<PLAIN>(s0, bb, arow);
                const bf16x8 b = *(const bf16x8*)(w0p + (kc << 5));
                if (kc & 1) g0B = MFMA(a, b, g0B); else g0A = MFMA(a, b, g0A);
            }
            #pragma unroll
            for (int qq = 0; qq < 4; ++qq)
                gsc0[wv*272 + (((lane >> 4) << 2) + qq)*17 + col16] = g0A[qq] + g0B[qq];
            asm volatile("s_waitcnt lgkmcnt(0)" ::: "memory");
            const float* g = gsc0 + wv*272 + rloc*17;
            const float ig = sigm(g[jj]), fg = sigm(g[4 + jj]);
            const float gt = tanhf(g[8 + jj]), og = sigm(g[12 + jj]);
            c0 = fg*c0 + ig*gt;
            unsigned v = f2bf(og * tanhf(c0));
            unsigned p = v | (__shfl_down(v, 1) << 16);
            ull_t all = ((ull_t)__shfl_down(p, 2) << 32) | (ull_t)p;
            if (jj == 0)
                __hip_atomic_store((ull_t*)(ring0 + (size_t)SLOT(t)*HBUF
                                            + (blk << 8) + (((wv << 4) + rloc) << 2)),
                                   all, RLX, AGENT);
            asm volatile("s_waitcnt vmcnt(0)" ::: "memory");
            {   // arrive: LDS agg across 4 waves; last wave publishes 8 flag replicas
                unsigned old = 0;
                if (lane == 0) old = atomicAdd(&scnt[0], 1u);
                old = (unsigned)__shfl((int)old, 0);
                if (old == 4u*(unsigned)t + 3u && lane < 8)
                    __hip_atomic_store(&bar[lane*256 + blk], (unsigned)(t + 1), RLX, AGENT);
            }
            PRIO(1);
            if (t + 1 < TT) {                       // slack: x-part for t+1
                g0A[0]=bias0; g0A[1]=bias0; g0A[2]=bias0; g0A[3]=bias0;
                g0B[0]=0.f;   g0B[1]=0.f;   g0B[2]=0.f;   g0B[3]=0.f;
                const float* xp = xs + (arow*TT + (t + 1))*INF + kgrp;
                #pragma unroll 4
                for (int kc = 0; kc < 16; ++kc) {
                    const float4 x0 = *(const float4*)(xp + (kc << 5));
                    const float4 x1 = *(const float4*)(xp + (kc << 5) + 4);
                    bf16x8 a;
                    a[0]=(short)f2bf(x0.x); a[1]=(short)f2bf(x0.y); a[2]=(short)f2bf(x0.z); a[3]=(short)f2bf(x0.w);
                    a[4]=(short)f2bf(x1.x); a[5]=(short)f2bf(x1.y); a[6]=(short)f2bf(x1.z); a[7]=(short)f2bf(x1.w);
                    const bf16x8 b = *(const bf16x8*)(w0p + ((32 + kc) << 5));
                    if (kc & 1) g0B = MFMA(a, b, g0B); else g0A = MFMA(a, b, g0A);
                }
            }
        }
    } else {
        // ---------- L1 worker: layer-1 step t-1 at loop t (prio 1 compute / 0 poll) ----------
        const float bias1 = bih1[grl] + bhh1[grl];
        float c1 = 0.f;
        for (int t = 1; t <= TT; ++t) {
            unsigned ncc1 = 0;
            if constexpr (DEPTH <= TT) {
                if (t - 1 >= DEPTH) ncc1 = (unsigned)((t - 1 - DEPTH)/8 + 1);
            }
            // phase 1: h1(t-2) part — own-layer gate (fills L0's wait window)
            PRIO(0);
            POLL3(0, t - 1, ncc1, 256);
            PRIO(1);
            f32x4 g1A = { bias1, bias1, bias1, bias1 }, g1B = { 0.f, 0.f, 0.f, 0.f };
            const u16* s1 = ring1 + (size_t)SLOT(t - 2)*HBUF;
            #pragma unroll 4
            for (int kc = 0; kc < 32; ++kc) {
                const int bb = (kgrp >> 2) + (kc << 3);
                const bf16x8 a = ld_pair<PLAIN>(s1, bb, arow);
                const bf16x8 b = *(const bf16x8*)(w1p + ((32 + kc) << 5));
                if (kc & 1) g1B = MFMA(a, b, g1B); else g1A = MFMA(a, b, g1A);
            }
            // phase 2: h0(t-1) part
            PRIO(0);
            POLL3(t, 0, 0, 256);
            PRIO(1);
            const u16* s0 = ring0 + (size_t)SLOT(t - 1)*HBUF;
            #pragma unroll 4
            for (int kc = 0; kc < 32; ++kc) {
                const int bb = (kgrp >> 2) + (kc << 3);
                const bf16x8 a = ld_pair<PLAIN>(s0, bb, arow);
                const bf16x8 b = *(const bf16x8*)(w1p + (kc << 5));
                if (kc & 1) g1B = MFMA(a, b, g1B); else g1A = MFMA(a, b, g1A);
            }
            #pragma unroll
            for (int qq = 0; qq < 4; ++qq)
                gsc1[wv*272 + (((lane >> 4) << 2) + qq)*17 + col16] = g1A[qq] + g1B[qq];
            asm volatile("s_waitcnt lgkmcnt(0)" ::: "memory");
            const float* g = gsc1 + wv*272 + rloc*17;
            const float ig = sigm(g[jj]), fg = sigm(g[4 + jj]);
            const float gt = tanhf(g[8 + jj]), og = sigm(g[12 + jj]);
            c1 = fg*c1 + ig*gt;
            unsigned v = f2bf(og * tanhf(c1));
            unsigned p = v | (__shfl_down(v, 1) << 16);
            ull_t all = ((ull_t)__shfl_down(p, 2) << 32) | (ull_t)p;
            if (jj == 0)
                __hip_atomic_store((ull_t*)(ring1 + (size_t)SLOT(t - 1)*HBUF
                                            + (blk << 8) + (((wv << 4) + rloc) << 2)),
                                   all, RLX, AGENT);
            asm volatile("s_waitcnt vmcnt(0)" ::: "memory");
            {
                unsigned old = 0;
                if (lane == 0) old = atomicAdd(&scnt[1], 1u);
                old = (unsigned)__shfl((int)old, 0);
                if (old == 4u*(unsigned)(t - 1) + 3u && lane < 8)
                    __hip_atomic_store(&bar[2048 + lane*256 + blk], (unsigned)t, RLX, AGENT);
            }
        }
    }
#undef SLOT
}

template<int DEPTH, bool PLAIN>
static void launch_tier(const float* xs, const float* Wih0, const float* Whh0,
                        const float* bih0, const float* bhh0,
                        const float* Wih1, const float* Whh1,
                        const float* bih1, const float* bhh1,
                        const float* Wcls, const float* bcls,
                        float* out, void* d_ws, hipStream_t stream) {
    u16* hws = (u16*)d_ws;
    size_t ringB = (size_t)DEPTH*HBUF*2;
    unsigned* bar = (unsigned*)((char*)d_ws + 2*ringB);
    (void)hipMemsetAsync(hws, 0, 2*(size_t)HBUF*2, stream);                 // h0(-1),h0(-2)=0
    (void)hipMemsetAsync((char*)hws + ringB, 0, 2*(size_t)HBUF*2, stream);  // h1(-1),h1(-2)=0
    (void)hipMemsetAsync(bar, 0, BAR_BYTES, stream);
    (void)hipFuncSetAttribute((const void*)lstm_persist<DEPTH, PLAIN>,
                              hipFuncAttributeMaxDynamicSharedMemorySize, SMEM_BYTES);
    lstm_persist<DEPTH, PLAIN><<<dim3(256), dim3(640), SMEM_BYTES, stream>>>(
        xs, Wih0, Whh0, bih0, bhh0, Wih1, Whh1, bih1, bhh1, Wcls, bcls,
        out, hws, bar);
}

extern "C" void kernel_launch(void* const* d_in, const int* in_sizes, int n_in,
                              void* d_out, int out_size, void* d_ws, size_t ws_size,
                              hipStream_t stream) {
    const float* xs   = (const float*)d_in[0];
    const float* Wih0 = (const float*)d_in[1];
    const float* Whh0 = (const float*)d_in[2];
    const float* bih0 = (const float*)d_in[3];
    const float* bhh0 = (const float*)d_in[4];
    const float* Wih1 = (const float*)d_in[5];
    const float* Whh1 = (const float*)d_in[6];
    const float* bih1 = (const float*)d_in[7];
    const float* bhh1 = (const float*)d_in[8];
    const float* Wcls = (const float*)d_in[9];
    const float* bcls = (const float*)d_in[10];
    float* out = (float*)d_out;

    auto need = [](int depth) { return (size_t)2*depth*HBUF*2 + BAR_BYTES; };

    if (ws_size >= need(258))       // never-reused slots: plain cached loads, no fences
        launch_tier<258, true >(xs,Wih0,Whh0,bih0,bhh0,Wih1,Whh1,bih1,bhh1,Wcls,bcls,out,d_ws,stream);
    else if (ws_size >= need(32))
        launch_tier< 32, false>(xs,Wih0,Whh0,bih0,bhh0,Wih1,Whh1,bih1,bhh1,Wcls,bcls,out,d_ws,stream);
    else if (ws_size >= need(16))
        launch_tier< 16, false>(xs,Wih0,Whh0,bih0,bhh0,Wih1,Whh1,bih1,bhh1,Wcls,bcls,out,d_ws,stream);
    else
        launch_tier<  8, false>(xs,Wih0,Whh0,bih0,bhh0,Wih1,Whh1,bih1,bhh1,Wcls,bcls,out,d_ws,stream);
}

// Round 15
// 4199.538 us; speedup vs baseline: 1.0074x; 1.0074x over previous
//
#include <hip/hip_runtime.h>

#define BB  64
#define TT  256
#define INF 512
#define HH  1024
#define CC  128

typedef __attribute__((ext_vector_type(8))) short bf16x8;
typedef __attribute__((ext_vector_type(4))) float f32x4;
typedef unsigned long long ull_t;
typedef unsigned short u16;

#define W0_LD 1544   // 1536+8
#define W1_LD 2056   // 2048+8
#define WC_LD 1032   // 1024+8
#define GSC_OFF (16*W0_LD + 16*W1_LD + 16*WC_LD)
#define SMEM_BYTES (GSC_OFF*2 + 2*(4*16*17)*4 + 64)

#define HBUF (BB*HH)                 // elements per h generation (128 KB)
#define BAR_BYTES 65536

#define AGENT __HIP_MEMORY_SCOPE_AGENT
#define RLX   __ATOMIC_RELAXED

__device__ __forceinline__ u16 f2bf(float f) {
    union { float f; unsigned u; } v; v.f = f;
    unsigned r = v.u + 0x7fffu + ((v.u >> 16) & 1u);   // RNE
    return (u16)(r >> 16);
}
__device__ __forceinline__ float sigm(float x) { return 1.f / (1.f + __expf(-x)); }

#define MFMA(a,b,c) __builtin_amdgcn_mfma_f32_16x16x32_bf16((a),(b),(c),0,0,0)
#define PRIO(n) __builtin_amdgcn_s_setprio(n)

// blocked h layout: [slot][block][row 0..63][col 0..3] — block region = 512 B,
// writer wave stores 16x8B = one full 128B line; readers: 2x8B per fragment.
template<bool PLAIN>
__device__ __forceinline__ bf16x8 ld_pair(const u16* slotbase, int bb, int ar) {
    union { ull_t u[2]; bf16x8 v; } x;
    const u16* p0 = slotbase + (bb << 8) + (ar << 2);
    if constexpr (PLAIN) {
        x.u[0] = *(const ull_t*)p0;           // written once before flag -> never stale
        x.u[1] = *(const ull_t*)(p0 + 256);
    } else {
        x.u[0] = __hip_atomic_load((const ull_t*)p0,         RLX, AGENT);
        x.u[1] = __hip_atomic_load((const ull_t*)(p0 + 256), RLX, AGENT);
    }
    return x.v;
}

// direct poll over per-block flags: one pass = 16-32B/lane from this block's replica.
// BK = FMA backoff length (pickup granularity vs fabric poll rate).
#define POLL3(nF0, nF1, nFC, BK) do { \
        const unsigned _n0 = (unsigned)(nF0), _n1 = (unsigned)(nF1), _nc = (unsigned)(nFC); \
        float _z = 1.f; \
        for (;;) { \
            bool _ok = true; \
            if (_n0) { \
                ull_t _a = __hip_atomic_load(f0p + (lane << 1),     RLX, AGENT); \
                ull_t _b = __hip_atomic_load(f0p + (lane << 1) + 1, RLX, AGENT); \
                _ok &= ((unsigned)_a >= _n0) && ((unsigned)(_a >> 32) >= _n0) \
                    && ((unsigned)_b >= _n0) && ((unsigned)(_b >> 32) >= _n0); \
            } \
            if (_n1) { \
                ull_t _a = __hip_atomic_load(f1p + (lane << 1),     RLX, AGENT); \
                ull_t _b = __hip_atomic_load(f1p + (lane << 1) + 1, RLX, AGENT); \
                _ok &= ((unsigned)_a >= _n1) && ((unsigned)(_a >> 32) >= _n1) \
                    && ((unsigned)_b >= _n1) && ((unsigned)(_b >> 32) >= _n1); \
            } \
            if (_nc && lane < 16) { \
                ull_t _a = __hip_atomic_load(fcp + lane, RLX, AGENT); \
                _ok &= ((unsigned)_a >= _nc) && ((unsigned)(_a >> 32) >= _nc); \
            } \
            if (__all(_ok)) break; \
            _Pragma("unroll 16") \
            for (int _i = 0; _i < (BK); ++_i) _z = __builtin_fmaf(_z, 0.99999988f, 1e-9f); \
            asm volatile("" :: "v"(_z)); \
        } \
        asm volatile("" ::: "memory"); \
    } while (0)

template<int DEPTH, bool PLAIN>
__global__ __launch_bounds__(768, 1)
void lstm_persist(const float* __restrict__ xs,
                  const float* __restrict__ Wih0, const float* __restrict__ Whh0,
                  const float* __restrict__ bih0, const float* __restrict__ bhh0,
                  const float* __restrict__ Wih1, const float* __restrict__ Whh1,
                  const float* __restrict__ bih1, const float* __restrict__ bhh1,
                  const float* __restrict__ Wcls, const float* __restrict__ bcls,
                  float* __restrict__ out,          // f32 [B][C][2T]
                  u16* __restrict__ hws,            // h slot arrays (blocked layout)
                  unsigned* __restrict__ bar)       // f0[8][256] f1[8][256] fc[8][64]
{
    extern __shared__ char smem[];
    u16* W0s = (u16*)smem;              // [16][W0_LD]  [W_hh0 | W_ih0]
    u16* W1s = W0s + 16*W0_LD;          // [16][W1_LD]  [W_ih1 | W_hh1]
    u16* WCs = W1s + 16*W1_LD;          // [16][WC_LD]  W_cls slice
    float* gsc0 = (float*)(smem + GSC_OFF*2);       // [4][16][17]
    float* gsc1 = gsc0 + 4*16*17;
    unsigned* scnt = (unsigned*)(gsc1 + 4*16*17);   // [0]=L0 arrivals, [1]=L1 arrivals

    const int blk   = blockIdx.x;       // owns h-cols 4*blk..4*blk+3 (both layers)
    const int tid   = threadIdx.x;
    const int wave  = tid >> 6;         // 0-3: L0, 4-7: L1, 8: cls, 9-11: heaters
    const int lane  = tid & 63;
    const int col16 = lane & 15;
    const int kgrp  = (lane >> 4) << 3;

    u16* ring0 = hws;                           // h0 value x at slot (x+2)%DEPTH
    u16* ring1 = hws + (size_t)DEPTH*HBUF;
    const ull_t* f0p = (const ull_t*)(bar + (blk & 7)*256);
    const ull_t* f1p = (const ull_t*)(bar + 2048 + (blk & 7)*256);
    const ull_t* fcp = (const ull_t*)(bar + 4096 + (blk & 7)*64);

#define SLOT(x) ((unsigned)(((x) + 2) % DEPTH))

    // ---- prologue: weights -> LDS (bf16)
    if (tid < 2) scnt[tid] = 0;
    for (int i = tid; i < 16*1536; i += 768) {
        int r = i / 1536, k = i - r*1536;
        int gr = 4*blk + (r & 3) + HH*(r >> 2);
        float v = (k < HH) ? Whh0[gr*HH + k] : Wih0[gr*INF + (k - HH)];
        W0s[r*W0_LD + k] = f2bf(v);
    }
    for (int i = tid; i < 16*2048; i += 768) {
        int r = i >> 11, k = i & 2047;
        int gr = 4*blk + (r & 3) + HH*(r >> 2);
        float v = (k < HH) ? Wih1[gr*HH + k] : Whh1[gr*HH + (k - HH)];
        W1s[r*W1_LD + k] = f2bf(v);
    }
    if (PLAIN || blk < 32) {
        int cb = (blk & 7) << 4;
        for (int i = tid; i < 16*1024; i += 768) {
            int r = i >> 10, k = i & 1023;
            WCs[r*WC_LD + k] = f2bf(Wcls[(cb + r)*HH + k]);
        }
    }
    __syncthreads();

    // ================= heater waves: ILP-saturating, prio 0 =================
    if (wave >= 9) {
        PRIO(0);
        const unsigned* myf1 = bar + 2048 + (blk & 7)*256 + blk;
        float a0 = 1.00f, a1 = 1.01f, a2 = 1.02f, a3 = 1.03f;
        float a4 = 1.04f, a5 = 1.05f, a6 = 1.06f, a7 = 1.07f;
        const float b = 0.99999988f, c = 1e-9f;
        for (;;) {
            #pragma unroll 32
            for (int i = 0; i < 256; ++i) {   // 2048 independent-stream FMAs
                a0 = __builtin_fmaf(a0, b, c); a1 = __builtin_fmaf(a1, b, c);
                a2 = __builtin_fmaf(a2, b, c); a3 = __builtin_fmaf(a3, b, c);
                a4 = __builtin_fmaf(a4, b, c); a5 = __builtin_fmaf(a5, b, c);
                a6 = __builtin_fmaf(a6, b, c); a7 = __builtin_fmaf(a7, b, c);
            }
            asm volatile("" :: "v"(a0), "v"(a1), "v"(a2), "v"(a3),
                              "v"(a4), "v"(a5), "v"(a6), "v"(a7));
            if (__hip_atomic_load(myf1, RLX, AGENT) >= (unsigned)TT) break;
        }
        return;
    }

    // ================= classifier wave (prio 0: idle slots only) =================
    if (wave == 8) {
        PRIO(0);
        const u16*  wcp   = WCs + col16*WC_LD + kgrp;
        const float biasc = bcls[((blk & 7) << 4) + col16];
        const int cc = ((blk & 7) << 4) + col16;
        const int cstart = PLAIN ? (blk >> 5) : 0;
        const int cstep  = PLAIN ? 8 : 1;
        const int R      = PLAIN ? ((blk & 31) >> 3) : (blk >> 3);
        const int arow2  = (R << 4) + col16;
        if (PLAIN || blk < 32) {
            for (int c = cstart; c < TT/8; c += cstep) {
                POLL3(0, 8*c + 8, 0, 256);       // h0/h1(8c..8c+7) final everywhere
                union { float2 f2[8]; f32x4 f4[4]; } o[4];
                #pragma unroll
                for (int tt = 0; tt < 8; ++tt) {
                    const int t = 8*c + tt;
                    const u16* s0 = ring0 + (size_t)SLOT(t)*HBUF;
                    const u16* s1 = ring1 + (size_t)SLOT(t)*HBUF;
                    f32x4 a0 = { biasc, biasc, biasc, biasc }, a1 = { 0.f, 0.f, 0.f, 0.f };
                    f32x4 b0 = { biasc, biasc, biasc, biasc }, b1 = { 0.f, 0.f, 0.f, 0.f };
                    #pragma unroll 4
                    for (int kc = 0; kc < 32; ++kc) {
                        const int bb = (kgrp >> 2) + (kc << 3);
                        const bf16x8 w  = *(const bf16x8*)(wcp + (kc << 5));
                        const bf16x8 x0 = ld_pair<PLAIN>(s0, bb, arow2);
                        const bf16x8 x1 = ld_pair<PLAIN>(s1, bb, arow2);
                        if (kc & 1) { a1 = MFMA(x0, w, a1); b1 = MFMA(x1, w, b1); }
                        else        { a0 = MFMA(x0, w, a0); b0 = MFMA(x1, w, b0); }
                    }
                    #pragma unroll
                    for (int q = 0; q < 4; ++q)
                        o[q].f2[tt] = make_float2(a0[q] + a1[q], b0[q] + b1[q]);
                }
                #pragma unroll
                for (int q = 0; q < 4; ++q) {
                    const int br = (R << 4) + ((lane >> 4) << 2) + q;
                    float* po = &out[(ull_t)(br*CC + cc)*(2*TT) + 16*c];
                    #pragma unroll
                    for (int s = 0; s < 4; ++s)
                        __builtin_nontemporal_store(o[q].f4[s], (f32x4*)(po + 4*s));
                }
                if (!PLAIN) {
                    asm volatile("s_waitcnt vmcnt(0)" ::: "memory");
                    if (lane < 8)
                        __hip_atomic_store(&bar[4096 + lane*64 + blk], (unsigned)(c + 1), RLX, AGENT);
                }
            }
        }
        return;
    }

    // ================= worker waves (prio 1) =================
    PRIO(1);
    const int wv   = wave & 3;
    const int arow = (wv << 4) + col16;
    const int rloc = lane >> 2, jj = lane & 3;
    const u16* w0p = W0s + col16*W0_LD + kgrp;
    const u16* w1p = W1s + col16*W1_LD + kgrp;
    const int  grl = 4*blk + (col16 & 3) + HH*(col16 >> 2);

    if (wave < 4) {
        // ---------- L0 worker: THE critical chain ----------
        const float bias0 = bih0[grl] + bhh0[grl];
        float c0 = 0.f;
        f32x4 g0A = { bias0, bias0, bias0, bias0 }, g0B = { 0.f, 0.f, 0.f, 0.f };
        {   // prime x-projection for t=0
            const float* xp = xs + (arow*TT + 0)*INF + kgrp;
            #pragma unroll 4
            for (int kc = 0; kc < 16; ++kc) {
                const float4 x0 = *(const float4*)(xp + (kc << 5));
                const float4 x1 = *(const float4*)(xp + (kc << 5) + 4);
                bf16x8 a;
                a[0]=(short)f2bf(x0.x); a[1]=(short)f2bf(x0.y); a[2]=(short)f2bf(x0.z); a[3]=(short)f2bf(x0.w);
                a[4]=(short)f2bf(x1.x); a[5]=(short)f2bf(x1.y); a[6]=(short)f2bf(x1.z); a[7]=(short)f2bf(x1.w);
                const bf16x8 b = *(const bf16x8*)(w0p + ((32 + kc) << 5));
                if (kc & 1) g0B = MFMA(a, b, g0B); else g0A = MFMA(a, b, g0A);
            }
        }
        for (int t = 0; t < TT; ++t) {
            unsigned n1c = 0, ncc = 0;
            if constexpr (DEPTH <= TT) {            // slot-reuse credits
                if (t >= DEPTH) { n1c = (unsigned)(t - DEPTH + 1);
                                  ncc = (unsigned)((t - DEPTH)/8 + 1); }
            }
            POLL3(t, n1c, ncc, 32);                 // h0(t-1) visible everywhere
            const u16* s0 = ring0 + (size_t)SLOT(t - 1)*HBUF;
            #pragma unroll 4
            for (int kc = 0; kc < 32; ++kc) {
                const int bb = (kgrp >> 2) + (kc << 3);
                const bf16x8 a = ld_pair<PLAIN>(s0, bb, arow);
                const bf16x8 b = *(const bf16x8*)(w0p + (kc << 5));
                if (kc & 1) g0B = MFMA(a, b, g0B); else g0A = MFMA(a, b, g0A);
            }
            #pragma unroll
            for (int qq = 0; qq < 4; ++qq)
                gsc0[wv*272 + (((lane >> 4) << 2) + qq)*17 + col16] = g0A[qq] + g0B[qq];
            asm volatile("s_waitcnt lgkmcnt(0)" ::: "memory");
            const float* g = gsc0 + wv*272 + rloc*17;
            const float ig = sigm(g[jj]), fg = sigm(g[4 + jj]);
            const float gt = tanhf(g[8 + jj]), og = sigm(g[12 + jj]);
            c0 = fg*c0 + ig*gt;
            unsigned v = f2bf(og * tanhf(c0));
            unsigned p = v | (__shfl_down(v, 1) << 16);
            ull_t all = ((ull_t)__shfl_down(p, 2) << 32) | (ull_t)p;
            if (jj == 0)
                __hip_atomic_store((ull_t*)(ring0 + (size_t)SLOT(t)*HBUF
                                            + (blk << 8) + (((wv << 4) + rloc) << 2)),
                                   all, RLX, AGENT);
            asm volatile("s_waitcnt vmcnt(0)" ::: "memory");
            {   // arrive: LDS agg across 4 waves; last wave publishes 8 flag replicas
                unsigned old = 0;
                if (lane == 0) old = atomicAdd(&scnt[0], 1u);
                old = (unsigned)__shfl((int)old, 0);
                if (old == 4u*(unsigned)t + 3u && lane < 8)
                    __hip_atomic_store(&bar[lane*256 + blk], (unsigned)(t + 1), RLX, AGENT);
            }
            if (t + 1 < TT) {                       // slack: x-part for t+1
                g0A[0]=bias0; g0A[1]=bias0; g0A[2]=bias0; g0A[3]=bias0;
                g0B[0]=0.f;   g0B[1]=0.f;   g0B[2]=0.f;   g0B[3]=0.f;
                const float* xp = xs + (arow*TT + (t + 1))*INF + kgrp;
                #pragma unroll 4
                for (int kc = 0; kc < 16; ++kc) {
                    const float4 x0 = *(const float4*)(xp + (kc << 5));
                    const float4 x1 = *(const float4*)(xp + (kc << 5) + 4);
                    bf16x8 a;
                    a[0]=(short)f2bf(x0.x); a[1]=(short)f2bf(x0.y); a[2]=(short)f2bf(x0.z); a[3]=(short)f2bf(x0.w);
                    a[4]=(short)f2bf(x1.x); a[5]=(short)f2bf(x1.y); a[6]=(short)f2bf(x1.z); a[7]=(short)f2bf(x1.w);
                    const bf16x8 b = *(const bf16x8*)(w0p + ((32 + kc) << 5));
                    if (kc & 1) g0B = MFMA(a, b, g0B); else g0A = MFMA(a, b, g0A);
                }
            }
        }
    } else {
        // ---------- L1 worker: layer-1 step t-1 at loop t ----------
        const float bias1 = bih1[grl] + bhh1[grl];
        float c1 = 0.f;
        for (int t = 1; t <= TT; ++t) {
            unsigned ncc1 = 0;
            if constexpr (DEPTH <= TT) {
                if (t - 1 >= DEPTH) ncc1 = (unsigned)((t - 1 - DEPTH)/8 + 1);
            }
            // phase 1: h1(t-2) part — own-layer gate (fills L0's wait window)
            POLL3(0, t - 1, ncc1, 256);
            f32x4 g1A = { bias1, bias1, bias1, bias1 }, g1B = { 0.f, 0.f, 0.f, 0.f };
            const u16* s1 = ring1 + (size_t)SLOT(t - 2)*HBUF;
            #pragma unroll 4
            for (int kc = 0; kc < 32; ++kc) {
                const int bb = (kgrp >> 2) + (kc << 3);
                const bf16x8 a = ld_pair<PLAIN>(s1, bb, arow);
                const bf16x8 b = *(const bf16x8*)(w1p + ((32 + kc) << 5));
                if (kc & 1) g1B = MFMA(a, b, g1B); else g1A = MFMA(a, b, g1A);
            }
            // phase 2: h0(t-1) part
            POLL3(t, 0, 0, 64);
            const u16* s0 = ring0 + (size_t)SLOT(t - 1)*HBUF;
            #pragma unroll 4
            for (int kc = 0; kc < 32; ++kc) {
                const int bb = (kgrp >> 2) + (kc << 3);
                const bf16x8 a = ld_pair<PLAIN>(s0, bb, arow);
                const bf16x8 b = *(const bf16x8*)(w1p + (kc << 5));
                if (kc & 1) g1B = MFMA(a, b, g1B); else g1A = MFMA(a, b, g1A);
            }
            #pragma unroll
            for (int qq = 0; qq < 4; ++qq)
                gsc1[wv*272 + (((lane >> 4) << 2) + qq)*17 + col16] = g1A[qq] + g1B[qq];
            asm volatile("s_waitcnt lgkmcnt(0)" ::: "memory");
            const float* g = gsc1 + wv*272 + rloc*17;
            const float ig = sigm(g[jj]), fg = sigm(g[4 + jj]);
            const float gt = tanhf(g[8 + jj]), og = sigm(g[12 + jj]);
            c1 = fg*c1 + ig*gt;
            unsigned v = f2bf(og * tanhf(c1));
            unsigned p = v | (__shfl_down(v, 1) << 16);
            ull_t all = ((ull_t)__shfl_down(p, 2) << 32) | (ull_t)p;
            if (jj == 0)
                __hip_atomic_store((ull_t*)(ring1 + (size_t)SLOT(t - 1)*HBUF
                                            + (blk << 8) + (((wv << 4) + rloc) << 2)),
                                   all, RLX, AGENT);
            asm volatile("s_waitcnt vmcnt(0)" ::: "memory");
            {
                unsigned old = 0;
                if (lane == 0) old = atomicAdd(&scnt[1], 1u);
                old = (unsigned)__shfl((int)old, 0);
                if (old == 4u*(unsigned)(t - 1) + 3u && lane < 8)
                    __hip_atomic_store(&bar[2048 + lane*256 + blk], (unsigned)t, RLX, AGENT);
            }
        }
    }
#undef SLOT
}

template<int DEPTH, bool PLAIN>
static void launch_tier(const float* xs, const float* Wih0, const float* Whh0,
                        const float* bih0, const float* bhh0,
                        const float* Wih1, const float* Whh1,
                        const float* bih1, const float* bhh1,
                        const float* Wcls, const float* bcls,
                        float* out, void* d_ws, hipStream_t stream) {
    u16* hws = (u16*)d_ws;
    size_t ringB = (size_t)DEPTH*HBUF*2;
    unsigned* bar = (unsigned*)((char*)d_ws + 2*ringB);
    (void)hipMemsetAsync(hws, 0, 2*(size_t)HBUF*2, stream);                 // h0(-1),h0(-2)=0
    (void)hipMemsetAsync((char*)hws + ringB, 0, 2*(size_t)HBUF*2, stream);  // h1(-1),h1(-2)=0
    (void)hipMemsetAsync(bar, 0, BAR_BYTES, stream);
    (void)hipFuncSetAttribute((const void*)lstm_persist<DEPTH, PLAIN>,
                              hipFuncAttributeMaxDynamicSharedMemorySize, SMEM_BYTES);
    lstm_persist<DEPTH, PLAIN><<<dim3(256), dim3(768), SMEM_BYTES, stream>>>(
        xs, Wih0, Whh0, bih0, bhh0, Wih1, Whh1, bih1, bhh1, Wcls, bcls,
        out, hws, bar);
}

extern "C" void kernel_launch(void* const* d_in, const int* in_sizes, int n_in,
                              void* d_out, int out_size, void* d_ws, size_t ws_size,
                              hipStream_t stream) {
    const float* xs   = (const float*)d_in[0];
    const float* Wih0 = (const float*)d_in[1];
    const float* Whh0 = (const float*)d_in[2];
    const float* bih0 = (const float*)d_in[3];
    const float* bhh0 = (const float*)d_in[4];
    const float* Wih1 = (const float*)d_in[5];
    const float* Whh1 = (const float*)d_in[6];
    const float* bih1 = (const float*)d_in[7];
    const float* bhh1 = (const float*)d_in[8];
    const float* Wcls = (const float*)d_in[9];
    const float* bcls = (const float*)d_in[10];
    float* out = (float*)d_out;

    auto need = [](int depth) { return (size_t)2*depth*HBUF*2 + BAR_BYTES; };

    if (ws_size >= need(258))       // never-reused slots: plain cached loads, no fences
        launch_tier<258, true >(xs,Wih0,Whh0,bih0,bhh0,Wih1,Whh1,bih1,bhh1,Wcls,bcls,out,d_ws,stream);
    else if (ws_size >= need(32))
        launch_tier< 32, false>(xs,Wih0,Whh0,bih0,bhh0,Wih1,Whh1,bih1,bhh1,Wcls,bcls,out,d_ws,stream);
    else if (ws_size >= need(16))
        launch_tier< 16, false>(xs,Wih0,Whh0,bih0,bhh0,Wih1,Whh1,bih1,bhh1,Wcls,bcls,out,d_ws,stream);
    else
        launch_tier<  8, false>(xs,Wih0,Whh0,bih0,bhh0,Wih1,Whh1,bih1,bhh1,Wcls,bcls,out,d_ws,stream);
}

// Round 16
// 4154.506 us; speedup vs baseline: 1.0183x; 1.0108x over previous
//
#include <hip/hip_runtime.h>

#define BB  64
#define TT  256
#define INF 512
#define HH  1024
#define CC  128

typedef __attribute__((ext_vector_type(8))) short bf16x8;
typedef __attribute__((ext_vector_type(4))) float f32x4;
typedef unsigned long long ull_t;
typedef unsigned short u16;

#define W0_LD 1544   // 1536+8
#define W1_LD 2056   // 2048+8
#define WC_LD 1032   // 1024+8
#define GSC_OFF (16*W0_LD + 16*W1_LD + 16*WC_LD)
#define SMEM_BYTES (GSC_OFF*2 + 2*(4*16*17)*4 + 64)

#define HBUF (BB*HH)                 // elements per h generation (128 KB)
#define BAR_BYTES 65536

#define AGENT __HIP_MEMORY_SCOPE_AGENT
#define RLX   __ATOMIC_RELAXED

__device__ __forceinline__ u16 f2bf(float f) {
    union { float f; unsigned u; } v; v.f = f;
    unsigned r = v.u + 0x7fffu + ((v.u >> 16) & 1u);   // RNE
    return (u16)(r >> 16);
}
__device__ __forceinline__ float sigm(float x) { return 1.f / (1.f + __expf(-x)); }

#define MFMA(a,b,c) __builtin_amdgcn_mfma_f32_16x16x32_bf16((a),(b),(c),0,0,0)

// blocked h layout: [slot][block][row 0..63][col 0..3] — block region = 512 B,
// writer wave stores 16x8B = one full 128B line; readers: 2x8B per fragment.
template<bool PLAIN>
__device__ __forceinline__ bf16x8 ld_pair(const u16* slotbase, int bb, int ar) {
    union { ull_t u[2]; bf16x8 v; } x;
    const u16* p0 = slotbase + (bb << 8) + (ar << 2);
    if constexpr (PLAIN) {
        x.u[0] = *(const ull_t*)p0;           // written once before flag -> never stale
        x.u[1] = *(const ull_t*)(p0 + 256);
    } else {
        x.u[0] = __hip_atomic_load((const ull_t*)p0,         RLX, AGENT);
        x.u[1] = __hip_atomic_load((const ull_t*)(p0 + 256), RLX, AGENT);
    }
    return x.v;
}

// direct poll over per-block flags: one pass = 16-32B/lane from this block's replica.
// BK = FMA backoff length (pickup granularity vs fabric poll rate).
#define POLL3(nF0, nF1, nFC, BK) do { \
        const unsigned _n0 = (unsigned)(nF0), _n1 = (unsigned)(nF1), _nc = (unsigned)(nFC); \
        float _z = 1.f; \
        for (;;) { \
            bool _ok = true; \
            if (_n0) { \
                ull_t _a = __hip_atomic_load(f0p + (lane << 1),     RLX, AGENT); \
                ull_t _b = __hip_atomic_load(f0p + (lane << 1) + 1, RLX, AGENT); \
                _ok &= ((unsigned)_a >= _n0) && ((unsigned)(_a >> 32) >= _n0) \
                    && ((unsigned)_b >= _n0) && ((unsigned)(_b >> 32) >= _n0); \
            } \
            if (_n1) { \
                ull_t _a = __hip_atomic_load(f1p + (lane << 1),     RLX, AGENT); \
                ull_t _b = __hip_atomic_load(f1p + (lane << 1) + 1, RLX, AGENT); \
                _ok &= ((unsigned)_a >= _n1) && ((unsigned)(_a >> 32) >= _n1) \
                    && ((unsigned)_b >= _n1) && ((unsigned)(_b >> 32) >= _n1); \
            } \
            if (_nc && lane < 16) { \
                ull_t _a = __hip_atomic_load(fcp + lane, RLX, AGENT); \
                _ok &= ((unsigned)_a >= _nc) && ((unsigned)(_a >> 32) >= _nc); \
            } \
            if (__all(_ok)) break; \
            _Pragma("unroll 16") \
            for (int _i = 0; _i < (BK); ++_i) _z = __builtin_fmaf(_z, 0.99999988f, 1e-9f); \
            asm volatile("" :: "v"(_z)); \
        } \
        asm volatile("" ::: "memory"); \
    } while (0)

template<int DEPTH, bool PLAIN>
__global__ __launch_bounds__(576, 1)
void lstm_persist(const float* __restrict__ xs,
                  const float* __restrict__ Wih0, const float* __restrict__ Whh0,
                  const float* __restrict__ bih0, const float* __restrict__ bhh0,
                  const float* __restrict__ Wih1, const float* __restrict__ Whh1,
                  const float* __restrict__ bih1, const float* __restrict__ bhh1,
                  const float* __restrict__ Wcls, const float* __restrict__ bcls,
                  float* __restrict__ out,          // f32 [B][C][2T]
                  u16* __restrict__ hws,            // h slot arrays (blocked layout)
                  unsigned* __restrict__ bar)       // f0[8][256] f1[8][256] fc[8][64]
{
    extern __shared__ char smem[];
    u16* W0s = (u16*)smem;              // [16][W0_LD]  [W_hh0 | W_ih0]
    u16* W1s = W0s + 16*W0_LD;          // [16][W1_LD]  [W_ih1 | W_hh1]
    u16* WCs = W1s + 16*W1_LD;          // [16][WC_LD]  W_cls slice
    float* gsc0 = (float*)(smem + GSC_OFF*2);       // [4][16][17]
    float* gsc1 = gsc0 + 4*16*17;
    unsigned* scnt = (unsigned*)(gsc1 + 4*16*17);   // [0]=L0 arrivals, [1]=L1 arrivals

    const int blk   = blockIdx.x;       // owns h-cols 4*blk..4*blk+3 (both layers)
    const int tid   = threadIdx.x;
    const int wave  = tid >> 6;         // 0-3: L0, 4-7: L1, 8: cls
    const int lane  = tid & 63;
    const int col16 = lane & 15;
    const int kgrp  = (lane >> 4) << 3;

    u16* ring0 = hws;                           // h0 value x at slot (x+2)%DEPTH
    u16* ring1 = hws + (size_t)DEPTH*HBUF;
    const ull_t* f0p = (const ull_t*)(bar + (blk & 7)*256);
    const ull_t* f1p = (const ull_t*)(bar + 2048 + (blk & 7)*256);
    const ull_t* fcp = (const ull_t*)(bar + 4096 + (blk & 7)*64);

#define SLOT(x) ((unsigned)(((x) + 2) % DEPTH))

    // ---- prologue: weights -> LDS (bf16)
    if (tid < 2) scnt[tid] = 0;
    for (int i = tid; i < 16*1536; i += 576) {
        int r = i / 1536, k = i - r*1536;
        int gr = 4*blk + (r & 3) + HH*(r >> 2);
        float v = (k < HH) ? Whh0[gr*HH + k] : Wih0[gr*INF + (k - HH)];
        W0s[r*W0_LD + k] = f2bf(v);
    }
    for (int i = tid; i < 16*2048; i += 576) {
        int r = i >> 11, k = i & 2047;
        int gr = 4*blk + (r & 3) + HH*(r >> 2);
        float v = (k < HH) ? Wih1[gr*HH + k] : Whh1[gr*HH + (k - HH)];
        W1s[r*W1_LD + k] = f2bf(v);
    }
    if (PLAIN || blk < 32) {
        int cb = (blk & 7) << 4;
        for (int i = tid; i < 16*1024; i += 576) {
            int r = i >> 10, k = i & 1023;
            WCs[r*WC_LD + k] = f2bf(Wcls[(cb + r)*HH + k]);
        }
    }
    __syncthreads();

    // ====== classifier wave: STREAMING — one timestep (64 MFMA, ~0.5us) per poll ======
    if (wave == 8) {
        const u16*  wcp   = WCs + col16*WC_LD + kgrp;
        const float biasc = bcls[((blk & 7) << 4) + col16];
        const int cc = ((blk & 7) << 4) + col16;
        const int cstart = PLAIN ? (blk >> 5) : 0;
        const int cstep  = PLAIN ? 8 : 1;
        const int R      = PLAIN ? ((blk & 31) >> 3) : (blk >> 3);
        const int arow2  = (R << 4) + col16;
        if (PLAIN || blk < 32) {
            for (int c = cstart; c < TT/8; c += cstep) {
                union { float2 f2[8]; f32x4 f4[4]; } o[4];
                #pragma unroll
                for (int tt = 0; tt < 8; ++tt) {
                    const int t = 8*c + tt;
                    POLL3(0, t + 1, 0, 64);      // h0/h1(t) final everywhere (per-step)
                    const u16* s0 = ring0 + (size_t)SLOT(t)*HBUF;
                    const u16* s1 = ring1 + (size_t)SLOT(t)*HBUF;
                    f32x4 a0 = { biasc, biasc, biasc, biasc }, a1 = { 0.f, 0.f, 0.f, 0.f };
                    f32x4 b0 = { biasc, biasc, biasc, biasc }, b1 = { 0.f, 0.f, 0.f, 0.f };
                    #pragma unroll 4
                    for (int kc = 0; kc < 32; ++kc) {
                        const int bb = (kgrp >> 2) + (kc << 3);
                        const bf16x8 w  = *(const bf16x8*)(wcp + (kc << 5));
                        const bf16x8 x0 = ld_pair<PLAIN>(s0, bb, arow2);
                        const bf16x8 x1 = ld_pair<PLAIN>(s1, bb, arow2);
                        if (kc & 1) { a1 = MFMA(x0, w, a1); b1 = MFMA(x1, w, b1); }
                        else        { a0 = MFMA(x0, w, a0); b0 = MFMA(x1, w, b0); }
                    }
                    #pragma unroll
                    for (int q = 0; q < 4; ++q)
                        o[q].f2[tt] = make_float2(a0[q] + a1[q], b0[q] + b1[q]);
                }
                #pragma unroll
                for (int q = 0; q < 4; ++q) {    // 64B bursts, locality preserved
                    const int br = (R << 4) + ((lane >> 4) << 2) + q;
                    float* po = &out[(ull_t)(br*CC + cc)*(2*TT) + 16*c];
                    #pragma unroll
                    for (int s = 0; s < 4; ++s)
                        __builtin_nontemporal_store(o[q].f4[s], (f32x4*)(po + 4*s));
                }
                if (!PLAIN) {
                    asm volatile("s_waitcnt vmcnt(0)" ::: "memory");
                    if (lane < 8)
                        __hip_atomic_store(&bar[4096 + lane*64 + blk], (unsigned)(c + 1), RLX, AGENT);
                }
            }
        }
        return;
    }

    // ================= worker waves =================
    const int wv   = wave & 3;
    const int arow = (wv << 4) + col16;
    const int rloc = lane >> 2, jj = lane & 3;
    const u16* w0p = W0s + col16*W0_LD + kgrp;
    const u16* w1p = W1s + col16*W1_LD + kgrp;
    const int  grl = 4*blk + (col16 & 3) + HH*(col16 >> 2);

    if (wave < 4) {
        // ---------- L0 worker: THE critical chain ----------
        const float bias0 = bih0[grl] + bhh0[grl];
        float c0 = 0.f;
        f32x4 g0A = { bias0, bias0, bias0, bias0 }, g0B = { 0.f, 0.f, 0.f, 0.f };
        {   // prime x-projection for t=0
            const float* xp = xs + (arow*TT + 0)*INF + kgrp;
            #pragma unroll 4
            for (int kc = 0; kc < 16; ++kc) {
                const float4 x0 = *(const float4*)(xp + (kc << 5));
                const float4 x1 = *(const float4*)(xp + (kc << 5) + 4);
                bf16x8 a;
                a[0]=(short)f2bf(x0.x); a[1]=(short)f2bf(x0.y); a[2]=(short)f2bf(x0.z); a[3]=(short)f2bf(x0.w);
                a[4]=(short)f2bf(x1.x); a[5]=(short)f2bf(x1.y); a[6]=(short)f2bf(x1.z); a[7]=(short)f2bf(x1.w);
                const bf16x8 b = *(const bf16x8*)(w0p + ((32 + kc) << 5));
                if (kc & 1) g0B = MFMA(a, b, g0B); else g0A = MFMA(a, b, g0A);
            }
        }
        for (int t = 0; t < TT; ++t) {
            unsigned n1c = 0, ncc = 0;
            if constexpr (DEPTH <= TT) {            // slot-reuse credits
                if (t >= DEPTH) { n1c = (unsigned)(t - DEPTH + 1);
                                  ncc = (unsigned)((t - DEPTH)/8 + 1); }
            }
            POLL3(t, n1c, ncc, 32);                 // h0(t-1) visible everywhere
            const u16* s0 = ring0 + (size_t)SLOT(t - 1)*HBUF;
            #pragma unroll 4
            for (int kc = 0; kc < 32; ++kc) {
                const int bb = (kgrp >> 2) + (kc << 3);
                const bf16x8 a = ld_pair<PLAIN>(s0, bb, arow);
                const bf16x8 b = *(const bf16x8*)(w0p + (kc << 5));
                if (kc & 1) g0B = MFMA(a, b, g0B); else g0A = MFMA(a, b, g0A);
            }
            #pragma unroll
            for (int qq = 0; qq < 4; ++qq)
                gsc0[wv*272 + (((lane >> 4) << 2) + qq)*17 + col16] = g0A[qq] + g0B[qq];
            asm volatile("s_waitcnt lgkmcnt(0)" ::: "memory");
            const float* g = gsc0 + wv*272 + rloc*17;
            const float ig = sigm(g[jj]), fg = sigm(g[4 + jj]);
            const float gt = tanhf(g[8 + jj]), og = sigm(g[12 + jj]);
            c0 = fg*c0 + ig*gt;
            unsigned v = f2bf(og * tanhf(c0));
            unsigned p = v | (__shfl_down(v, 1) << 16);
            ull_t all = ((ull_t)__shfl_down(p, 2) << 32) | (ull_t)p;
            if (jj == 0)
                __hip_atomic_store((ull_t*)(ring0 + (size_t)SLOT(t)*HBUF
                                            + (blk << 8) + (((wv << 4) + rloc) << 2)),
                                   all, RLX, AGENT);
            asm volatile("s_waitcnt vmcnt(0)" ::: "memory");
            {   // arrive: LDS agg across 4 waves; last wave publishes 8 flag replicas
                unsigned old = 0;
                if (lane == 0) old = atomicAdd(&scnt[0], 1u);
                old = (unsigned)__shfl((int)old, 0);
                if (old == 4u*(unsigned)t + 3u && lane < 8)
                    __hip_atomic_store(&bar[lane*256 + blk], (unsigned)(t + 1), RLX, AGENT);
            }
            if (t + 1 < TT) {                       // slack: x-part for t+1
                g0A[0]=bias0; g0A[1]=bias0; g0A[2]=bias0; g0A[3]=bias0;
                g0B[0]=0.f;   g0B[1]=0.f;   g0B[2]=0.f;   g0B[3]=0.f;
                const float* xp = xs + (arow*TT + (t + 1))*INF + kgrp;
                #pragma unroll 4
                for (int kc = 0; kc < 16; ++kc) {
                    const float4 x0 = *(const float4*)(xp + (kc << 5));
                    const float4 x1 = *(const float4*)(xp + (kc << 5) + 4);
                    bf16x8 a;
                    a[0]=(short)f2bf(x0.x); a[1]=(short)f2bf(x0.y); a[2]=(short)f2bf(x0.z); a[3]=(short)f2bf(x0.w);
                    a[4]=(short)f2bf(x1.x); a[5]=(short)f2bf(x1.y); a[6]=(short)f2bf(x1.z); a[7]=(short)f2bf(x1.w);
                    const bf16x8 b = *(const bf16x8*)(w0p + ((32 + kc) << 5));
                    if (kc & 1) g0B = MFMA(a, b, g0B); else g0A = MFMA(a, b, g0A);
                }
            }
        }
    } else {
        // ---------- L1 worker: layer-1 step t-1 at loop t ----------
        const float bias1 = bih1[grl] + bhh1[grl];
        float c1 = 0.f;
        for (int t = 1; t <= TT; ++t) {
            unsigned ncc1 = 0;
            if constexpr (DEPTH <= TT) {
                if (t - 1 >= DEPTH) ncc1 = (unsigned)((t - 1 - DEPTH)/8 + 1);
            }
            // phase 1: h1(t-2) part — own-layer gate (fills L0's wait window)
            POLL3(0, t - 1, ncc1, 256);
            f32x4 g1A = { bias1, bias1, bias1, bias1 }, g1B = { 0.f, 0.f, 0.f, 0.f };
            const u16* s1 = ring1 + (size_t)SLOT(t - 2)*HBUF;
            #pragma unroll 4
            for (int kc = 0; kc < 32; ++kc) {
                const int bb = (kgrp >> 2) + (kc << 3);
                const bf16x8 a = ld_pair<PLAIN>(s1, bb, arow);
                const bf16x8 b = *(const bf16x8*)(w1p + ((32 + kc) << 5));
                if (kc & 1) g1B = MFMA(a, b, g1B); else g1A = MFMA(a, b, g1A);
            }
            // phase 2: h0(t-1) part
            POLL3(t, 0, 0, 64);
            const u16* s0 = ring0 + (size_t)SLOT(t - 1)*HBUF;
            #pragma unroll 4
            for (int kc = 0; kc < 32; ++kc) {
                const int bb = (kgrp >> 2) + (kc << 3);
                const bf16x8 a = ld_pair<PLAIN>(s0, bb, arow);
                const bf16x8 b = *(const bf16x8*)(w1p + (kc << 5));
                if (kc & 1) g1B = MFMA(a, b, g1B); else g1A = MFMA(a, b, g1A);
            }
            #pragma unroll
            for (int qq = 0; qq < 4; ++qq)
                gsc1[wv*272 + (((lane >> 4) << 2) + qq)*17 + col16] = g1A[qq] + g1B[qq];
            asm volatile("s_waitcnt lgkmcnt(0)" ::: "memory");
            const float* g = gsc1 + wv*272 + rloc*17;
            const float ig = sigm(g[jj]), fg = sigm(g[4 + jj]);
            const float gt = tanhf(g[8 + jj]), og = sigm(g[12 + jj]);
            c1 = fg*c1 + ig*gt;
            unsigned v = f2bf(og * tanhf(c1));
            unsigned p = v | (__shfl_down(v, 1) << 16);
            ull_t all = ((ull_t)__shfl_down(p, 2) << 32) | (ull_t)p;
            if (jj == 0)
                __hip_atomic_store((ull_t*)(ring1 + (size_t)SLOT(t - 1)*HBUF
                                            + (blk << 8) + (((wv << 4) + rloc) << 2)),
                                   all, RLX, AGENT);
            asm volatile("s_waitcnt vmcnt(0)" ::: "memory");
            {
                unsigned old = 0;
                if (lane == 0) old = atomicAdd(&scnt[1], 1u);
                old = (unsigned)__shfl((int)old, 0);
                if (old == 4u*(unsigned)(t - 1) + 3u && lane < 8)
                    __hip_atomic_store(&bar[2048 + lane*256 + blk], (unsigned)t, RLX, AGENT);
            }
        }
    }
#undef SLOT
}

template<int DEPTH, bool PLAIN>
static void launch_tier(const float* xs, const float* Wih0, const float* Whh0,
                        const float* bih0, const float* bhh0,
                        const float* Wih1, const float* Whh1,
                        const float* bih1, const float* bhh1,
                        const float* Wcls, const float* bcls,
                        float* out, void* d_ws, hipStream_t stream) {
    u16* hws = (u16*)d_ws;
    size_t ringB = (size_t)DEPTH*HBUF*2;
    unsigned* bar = (unsigned*)((char*)d_ws + 2*ringB);
    (void)hipMemsetAsync(hws, 0, 2*(size_t)HBUF*2, stream);                 // h0(-1),h0(-2)=0
    (void)hipMemsetAsync((char*)hws + ringB, 0, 2*(size_t)HBUF*2, stream);  // h1(-1),h1(-2)=0
    (void)hipMemsetAsync(bar, 0, BAR_BYTES, stream);
    (void)hipFuncSetAttribute((const void*)lstm_persist<DEPTH, PLAIN>,
                              hipFuncAttributeMaxDynamicSharedMemorySize, SMEM_BYTES);
    lstm_persist<DEPTH, PLAIN><<<dim3(256), dim3(576), SMEM_BYTES, stream>>>(
        xs, Wih0, Whh0, bih0, bhh0, Wih1, Whh1, bih1, bhh1, Wcls, bcls,
        out, hws, bar);
}

extern "C" void kernel_launch(void* const* d_in, const int* in_sizes, int n_in,
                              void* d_out, int out_size, void* d_ws, size_t ws_size,
                              hipStream_t stream) {
    const float* xs   = (const float*)d_in[0];
    const float* Wih0 = (const float*)d_in[1];
    const float* Whh0 = (const float*)d_in[2];
    const float* bih0 = (const float*)d_in[3];
    const float* bhh0 = (const float*)d_in[4];
    const float* Wih1 = (const float*)d_in[5];
    const float* Whh1 = (const float*)d_in[6];
    const float* bih1 = (const float*)d_in[7];
    const float* bhh1 = (const float*)d_in[8];
    const float* Wcls = (const float*)d_in[9];
    const float* bcls = (const float*)d_in[10];
    float* out = (float*)d_out;

    auto need = [](int depth) { return (size_t)2*depth*HBUF*2 + BAR_BYTES; };

    if (ws_size >= need(258))       // never-reused slots: plain cached loads, no fences
        launch_tier<258, true >(xs,Wih0,Whh0,bih0,bhh0,Wih1,Whh1,bih1,bhh1,Wcls,bcls,out,d_ws,stream);
    else if (ws_size >= need(32))
        launch_tier< 32, false>(xs,Wih0,Whh0,bih0,bhh0,Wih1,Whh1,bih1,bhh1,Wcls,bcls,out,d_ws,stream);
    else if (ws_size >= need(16))
        launch_tier< 16, false>(xs,Wih0,Whh0,bih0,bhh0,Wih1,Whh1,bih1,bhh1,Wcls,bcls,out,d_ws,stream);
    else
        launch_tier<  8, false>(xs,Wih0,Whh0,bih0,bhh0,Wih1,Whh1,bih1,bhh1,Wcls,bcls,out,d_ws,stream);
}